// Round 5
// baseline (10807.478 us; speedup 1.0000x reference)
//
#include <hip/hip_runtime.h>

#define NWG 128
#define TSTEPS 512

typedef __attribute__((ext_vector_type(8))) short short8;
typedef __attribute__((ext_vector_type(4))) float f32x4;

// ---- LDS offsets (bytes) ----
#define T0_OFF   0            // [z8|r8] rows, K=1536, 48 ksteps * 1KB = 48 KB
#define T1_OFF   49152        // [o8|c8] rows, K=1536 (c zero for k>=512), 48 KB
#define T2_OFF   98304        // [c8|0] rows, rc-range K=1024, 32 ksteps = 32 KB
#define ZBUF_OFF 135168       // [8][64] f32
#define OBUF_OFF 137216
#define XCB_OFF  139264
#define CST_OFF  141312
#define RCS_OFF  143360
#define HST_OFF  145408
#define BIAS_OFF 147456       // [32] f32
#define LDS_BYTES 147584

__device__ inline unsigned short f2bf(float f) {
  unsigned int b = __float_as_uint(f);
  return (unsigned short)((b + 0x7FFFu + ((b >> 16) & 1u)) >> 16);  // RNE
}
__device__ inline float sigm(float x) { return 1.f / (1.f + __expf(-x)); }
__device__ inline float tanh_f(float x) { float e = __expf(2.f * x); return 1.f - 2.f / (e + 1.f); }

// ---- fine-grained coherent (LLC-level) access helpers: no wbl2 / no inv ----
__device__ inline void cstore16(void* p, short8 v) {
  asm volatile("global_store_dwordx4 %0, %1, off sc0 sc1" :: "v"(p), "v"(v) : "memory");
}
__device__ inline void cstore16f(void* p, f32x4 v) {
  asm volatile("global_store_dwordx4 %0, %1, off sc0 sc1" :: "v"(p), "v"(v) : "memory");
}
__device__ inline void cstore4(void* p, int v) {
  asm volatile("global_store_dword %0, %1, off sc0 sc1" :: "v"(p), "v"(v) : "memory");
}
__device__ inline int cload4(const void* p) {
  int v;
  asm volatile("global_load_dword %0, %1, off sc0 sc1\n\ts_waitcnt vmcnt(0)"
               : "=&v"(v) : "v"(p) : "memory");
  return v;
}
__device__ inline void vmdrain() {
  asm volatile("s_waitcnt vmcnt(0)" ::: "memory");
}

// 32 coherent 16B loads, stride 64B, NO trailing wait (pipelined; a later
// wait-carrying block covers these via vmcnt(0)). Early-clobber mandatory.
__device__ inline void cload32_nw(const unsigned short* p, short8* a) {
  asm volatile(
    "global_load_dwordx4 %0,  %32, off sc0 sc1\n\t"
    "global_load_dwordx4 %1,  %32, off offset:64 sc0 sc1\n\t"
    "global_load_dwordx4 %2,  %32, off offset:128 sc0 sc1\n\t"
    "global_load_dwordx4 %3,  %32, off offset:192 sc0 sc1\n\t"
    "global_load_dwordx4 %4,  %32, off offset:256 sc0 sc1\n\t"
    "global_load_dwordx4 %5,  %32, off offset:320 sc0 sc1\n\t"
    "global_load_dwordx4 %6,  %32, off offset:384 sc0 sc1\n\t"
    "global_load_dwordx4 %7,  %32, off offset:448 sc0 sc1\n\t"
    "global_load_dwordx4 %8,  %32, off offset:512 sc0 sc1\n\t"
    "global_load_dwordx4 %9,  %32, off offset:576 sc0 sc1\n\t"
    "global_load_dwordx4 %10, %32, off offset:640 sc0 sc1\n\t"
    "global_load_dwordx4 %11, %32, off offset:704 sc0 sc1\n\t"
    "global_load_dwordx4 %12, %32, off offset:768 sc0 sc1\n\t"
    "global_load_dwordx4 %13, %32, off offset:832 sc0 sc1\n\t"
    "global_load_dwordx4 %14, %32, off offset:896 sc0 sc1\n\t"
    "global_load_dwordx4 %15, %32, off offset:960 sc0 sc1\n\t"
    "global_load_dwordx4 %16, %32, off offset:1024 sc0 sc1\n\t"
    "global_load_dwordx4 %17, %32, off offset:1088 sc0 sc1\n\t"
    "global_load_dwordx4 %18, %32, off offset:1152 sc0 sc1\n\t"
    "global_load_dwordx4 %19, %32, off offset:1216 sc0 sc1\n\t"
    "global_load_dwordx4 %20, %32, off offset:1280 sc0 sc1\n\t"
    "global_load_dwordx4 %21, %32, off offset:1344 sc0 sc1\n\t"
    "global_load_dwordx4 %22, %32, off offset:1408 sc0 sc1\n\t"
    "global_load_dwordx4 %23, %32, off offset:1472 sc0 sc1\n\t"
    "global_load_dwordx4 %24, %32, off offset:1536 sc0 sc1\n\t"
    "global_load_dwordx4 %25, %32, off offset:1600 sc0 sc1\n\t"
    "global_load_dwordx4 %26, %32, off offset:1664 sc0 sc1\n\t"
    "global_load_dwordx4 %27, %32, off offset:1728 sc0 sc1\n\t"
    "global_load_dwordx4 %28, %32, off offset:1792 sc0 sc1\n\t"
    "global_load_dwordx4 %29, %32, off offset:1856 sc0 sc1\n\t"
    "global_load_dwordx4 %30, %32, off offset:1920 sc0 sc1\n\t"
    "global_load_dwordx4 %31, %32, off offset:1984 sc0 sc1"
    : "=&v"(a[0]), "=&v"(a[1]), "=&v"(a[2]), "=&v"(a[3]),
      "=&v"(a[4]), "=&v"(a[5]), "=&v"(a[6]), "=&v"(a[7]),
      "=&v"(a[8]), "=&v"(a[9]), "=&v"(a[10]), "=&v"(a[11]),
      "=&v"(a[12]), "=&v"(a[13]), "=&v"(a[14]), "=&v"(a[15]),
      "=&v"(a[16]), "=&v"(a[17]), "=&v"(a[18]), "=&v"(a[19]),
      "=&v"(a[20]), "=&v"(a[21]), "=&v"(a[22]), "=&v"(a[23]),
      "=&v"(a[24]), "=&v"(a[25]), "=&v"(a[26]), "=&v"(a[27]),
      "=&v"(a[28]), "=&v"(a[29]), "=&v"(a[30]), "=&v"(a[31])
    : "v"(p)
    : "memory");
}

// 32 coherent 16B loads, stride 64B, WITH trailing vmcnt(0).
__device__ inline void cload32_w(const unsigned short* p, short8* a) {
  asm volatile(
    "global_load_dwordx4 %0,  %32, off sc0 sc1\n\t"
    "global_load_dwordx4 %1,  %32, off offset:64 sc0 sc1\n\t"
    "global_load_dwordx4 %2,  %32, off offset:128 sc0 sc1\n\t"
    "global_load_dwordx4 %3,  %32, off offset:192 sc0 sc1\n\t"
    "global_load_dwordx4 %4,  %32, off offset:256 sc0 sc1\n\t"
    "global_load_dwordx4 %5,  %32, off offset:320 sc0 sc1\n\t"
    "global_load_dwordx4 %6,  %32, off offset:384 sc0 sc1\n\t"
    "global_load_dwordx4 %7,  %32, off offset:448 sc0 sc1\n\t"
    "global_load_dwordx4 %8,  %32, off offset:512 sc0 sc1\n\t"
    "global_load_dwordx4 %9,  %32, off offset:576 sc0 sc1\n\t"
    "global_load_dwordx4 %10, %32, off offset:640 sc0 sc1\n\t"
    "global_load_dwordx4 %11, %32, off offset:704 sc0 sc1\n\t"
    "global_load_dwordx4 %12, %32, off offset:768 sc0 sc1\n\t"
    "global_load_dwordx4 %13, %32, off offset:832 sc0 sc1\n\t"
    "global_load_dwordx4 %14, %32, off offset:896 sc0 sc1\n\t"
    "global_load_dwordx4 %15, %32, off offset:960 sc0 sc1\n\t"
    "global_load_dwordx4 %16, %32, off offset:1024 sc0 sc1\n\t"
    "global_load_dwordx4 %17, %32, off offset:1088 sc0 sc1\n\t"
    "global_load_dwordx4 %18, %32, off offset:1152 sc0 sc1\n\t"
    "global_load_dwordx4 %19, %32, off offset:1216 sc0 sc1\n\t"
    "global_load_dwordx4 %20, %32, off offset:1280 sc0 sc1\n\t"
    "global_load_dwordx4 %21, %32, off offset:1344 sc0 sc1\n\t"
    "global_load_dwordx4 %22, %32, off offset:1408 sc0 sc1\n\t"
    "global_load_dwordx4 %23, %32, off offset:1472 sc0 sc1\n\t"
    "global_load_dwordx4 %24, %32, off offset:1536 sc0 sc1\n\t"
    "global_load_dwordx4 %25, %32, off offset:1600 sc0 sc1\n\t"
    "global_load_dwordx4 %26, %32, off offset:1664 sc0 sc1\n\t"
    "global_load_dwordx4 %27, %32, off offset:1728 sc0 sc1\n\t"
    "global_load_dwordx4 %28, %32, off offset:1792 sc0 sc1\n\t"
    "global_load_dwordx4 %29, %32, off offset:1856 sc0 sc1\n\t"
    "global_load_dwordx4 %30, %32, off offset:1920 sc0 sc1\n\t"
    "global_load_dwordx4 %31, %32, off offset:1984 sc0 sc1\n\t"
    "s_waitcnt vmcnt(0)"
    : "=&v"(a[0]), "=&v"(a[1]), "=&v"(a[2]), "=&v"(a[3]),
      "=&v"(a[4]), "=&v"(a[5]), "=&v"(a[6]), "=&v"(a[7]),
      "=&v"(a[8]), "=&v"(a[9]), "=&v"(a[10]), "=&v"(a[11]),
      "=&v"(a[12]), "=&v"(a[13]), "=&v"(a[14]), "=&v"(a[15]),
      "=&v"(a[16]), "=&v"(a[17]), "=&v"(a[18]), "=&v"(a[19]),
      "=&v"(a[20]), "=&v"(a[21]), "=&v"(a[22]), "=&v"(a[23]),
      "=&v"(a[24]), "=&v"(a[25]), "=&v"(a[26]), "=&v"(a[27]),
      "=&v"(a[28]), "=&v"(a[29]), "=&v"(a[30]), "=&v"(a[31])
    : "v"(p)
    : "memory");
}

// 16 coherent 16B loads, stride 64B, WITH trailing vmcnt(0) (covers any
// earlier no-wait block too, since vmcnt(0) drains the whole wave queue).
__device__ inline void cload16_w(const unsigned short* p, short8* a) {
  asm volatile(
    "global_load_dwordx4 %0,  %16, off sc0 sc1\n\t"
    "global_load_dwordx4 %1,  %16, off offset:64 sc0 sc1\n\t"
    "global_load_dwordx4 %2,  %16, off offset:128 sc0 sc1\n\t"
    "global_load_dwordx4 %3,  %16, off offset:192 sc0 sc1\n\t"
    "global_load_dwordx4 %4,  %16, off offset:256 sc0 sc1\n\t"
    "global_load_dwordx4 %5,  %16, off offset:320 sc0 sc1\n\t"
    "global_load_dwordx4 %6,  %16, off offset:384 sc0 sc1\n\t"
    "global_load_dwordx4 %7,  %16, off offset:448 sc0 sc1\n\t"
    "global_load_dwordx4 %8,  %16, off offset:512 sc0 sc1\n\t"
    "global_load_dwordx4 %9,  %16, off offset:576 sc0 sc1\n\t"
    "global_load_dwordx4 %10, %16, off offset:640 sc0 sc1\n\t"
    "global_load_dwordx4 %11, %16, off offset:704 sc0 sc1\n\t"
    "global_load_dwordx4 %12, %16, off offset:768 sc0 sc1\n\t"
    "global_load_dwordx4 %13, %16, off offset:832 sc0 sc1\n\t"
    "global_load_dwordx4 %14, %16, off offset:896 sc0 sc1\n\t"
    "global_load_dwordx4 %15, %16, off offset:960 sc0 sc1\n\t"
    "s_waitcnt vmcnt(0)"
    : "=&v"(a[0]), "=&v"(a[1]), "=&v"(a[2]), "=&v"(a[3]),
      "=&v"(a[4]), "=&v"(a[5]), "=&v"(a[6]), "=&v"(a[7]),
      "=&v"(a[8]), "=&v"(a[9]), "=&v"(a[10]), "=&v"(a[11]),
      "=&v"(a[12]), "=&v"(a[13]), "=&v"(a[14]), "=&v"(a[15])
    : "v"(p)
    : "memory");
}

__global__ void __launch_bounds__(256) lmgru_kernel(
    const float* __restrict__ x,
    const float* __restrict__ Wz, const float* __restrict__ bz,
    const float* __restrict__ Wr, const float* __restrict__ br,
    const float* __restrict__ Wc, const float* __restrict__ bc,
    const float* __restrict__ Wo, const float* __restrict__ bo,
    const float* __restrict__ fcw, const float* __restrict__ fcb,
    float* __restrict__ out, char* __restrict__ ws)
{
  extern __shared__ char lds[];
  const int tid  = threadIdx.x;
  const int wg   = blockIdx.x;
  const int lane = tid & 63;
  const int q    = tid >> 6;          // wave id 0..3 = M-tile (16 batches each)

  // ---- workspace layout ----
  unsigned short* hbuf  = (unsigned short*)ws;               // [2][64][1024] bf16
  unsigned short* rcbuf = (unsigned short*)(ws + 262144);    // [2][64][1024] bf16
  unsigned short* xring = (unsigned short*)(ws + 524288);    // [2][64][512]  bf16
  float*          h32   = (float*)(ws + 655360);             // [64][1024] f32
  int* hctr     = (int*)(ws + 917504);           // epoch counter: h publishes
  int* rcctr    = (int*)(ws + 917504 + 128);     // epoch counter: rc publishes
  int* initflag = (int*)(ws + 917504 + 256);     // [128], poison(neg) -> 0

  float* zbuf = (float*)(lds + ZBUF_OFF);
  float* obuf = (float*)(lds + OBUF_OFF);
  float* xcb  = (float*)(lds + XCB_OFF);
  float* cst  = (float*)(lds + CST_OFF);
  float* rcs  = (float*)(lds + RCS_OFF);
  float* hst  = (float*)(lds + HST_OFF);
  float* bias = (float*)(lds + BIAS_OFF);

  const float* Wg[4] = {Wz, Wr, Wo, Wc};   // n-row layout: [z8 r8 o8 c8]

  // ================= INIT: build fragment-ordered bf16 weights in LDS =================
  for (int it = 0; it < 12; ++it) {
    int slot = tid + 256 * it;               // 3072 slots
    int s = slot >> 6, l = slot & 63;
    int nn = l & 15, kg = (l >> 4) & 3;
    int k = 32 * s + kg * 8;
    int g = (nn < 8) ? 0 : 1;
    const float* src = Wg[g] + (8 * wg + (nn & 7)) * 1536 + k;
    short8 pk;
    #pragma unroll
    for (int j = 0; j < 8; ++j) pk[j] = (short)f2bf(src[j]);
    *(short8*)(lds + T0_OFF + s * 1024 + l * 16) = pk;
  }
  for (int it = 0; it < 12; ++it) {
    int slot = tid + 256 * it;
    int s = slot >> 6, l = slot & 63;
    int nn = l & 15, kg = (l >> 4) & 3;
    int k = 32 * s + kg * 8;
    int g = (nn < 8) ? 2 : 3;
    short8 pk = {};
    if (g == 2 || k < 512) {
      const float* src = Wg[g] + (8 * wg + (nn & 7)) * 1536 + k;
      #pragma unroll
      for (int j = 0; j < 8; ++j) pk[j] = (short)f2bf(src[j]);
    }
    *(short8*)(lds + T1_OFF + s * 1024 + l * 16) = pk;
  }
  for (int it = 0; it < 8; ++it) {
    int slot = tid + 256 * it;               // 2048 slots
    int s = slot >> 6, l = slot & 63;
    int nn = l & 15, kg = (l >> 4) & 3;
    int k = 32 * s + kg * 8;                 // 0..1023
    short8 pk = {};
    if (nn < 8) {
      const float* src = Wc + (8 * wg + nn) * 1536 + 512 + k;
      #pragma unroll
      for (int j = 0; j < 8; ++j) pk[j] = (short)f2bf(src[j]);
    }
    *(short8*)(lds + T2_OFF + s * 1024 + l * 16) = pk;
  }
  if (tid < 32) {
    const float* Bg[4] = {bz, br, bo, bc};
    bias[tid] = Bg[tid >> 3][8 * wg + (tid & 7)];
  }
  cst[tid] = 0.f; cst[tid + 256] = 0.f;      // c state = 0
  if (tid < 64) {                            // h_0 = 0 (parity 0) -- coherent
    short8 z8 = {};
    cstore16(hbuf + tid * 1024 + 8 * wg, z8);
  }
  if (tid < 32) {                            // x for step 1 -> xring parity 1 (coherent)
    int e = wg * 256 + tid * 8;
    int b = e >> 9, f = e & 511;
    const float* xs = x + b * 262144 + f;
    short8 pk;
    #pragma unroll
    for (int j = 0; j < 8; ++j) pk[j] = (short)f2bf(xs[j]);
    cstore16(xring + 32768 + b * 512 + f, pk);
  }
  if (wg == 0 && tid == 0) {                 // zero epoch counters (poisoned 0xAA)
    cstore4(hctr, 0);
    cstore4(rcctr, 0);
  }
  __syncthreads();
  if (tid == 0) {                            // release init: all this WG's coherent
    vmdrain();                               // stores (and WG0's ctr zeroing) acked
    cstore4(&initflag[wg], 0);
  }
  // one-time all-to-all: wait every WG's init (incl. counter zeroing)
  if (tid < 128) {
    const int* fp = &initflag[tid];
    while (cload4(fp) < 0) __builtin_amdgcn_s_sleep(1);
  }
  __syncthreads();

  const int nn    = lane & 15;             // fragment col (C) / A row offset
  const int kg8   = ((lane >> 4) & 3) * 8; // A-frag k offset within kstep
  const int rbase = ((lane >> 4) & 3) * 4; // C row base
  const int brow  = 16 * q + nn;           // this lane's A row (batch)

  // ================= RECURRENCE: 2 epoch-counter rounds per step =================
  for (int t = 1; t <= TSTEPS; ++t) {
    const int pc = t & 1, pp = (t - 1) & 1;

    // ---------- ROUND 1: z,r,o preacts + Xc (needs h(t-1) from all WGs) ----------
    if (tid == 0) {
      const int target = 128 * (t - 1);
      while (cload4(hctr) < target) __builtin_amdgcn_s_sleep(1);
    }
    __syncthreads();

    {
      f32x4 acc0 = {0.f, 0.f, 0.f, 0.f}, acc1 = {0.f, 0.f, 0.f, 0.f};
      const unsigned short* hb = hbuf + pp * 65536 + brow * 1024 + kg8;
      const unsigned short* xr = xring + pc * 32768 + brow * 512 + kg8;
      short8 ah[32], ax[16];
      cload32_nw(hb, ah);        // issue h loads (no wait)
      cload16_w(xr, ax);         // issue x loads; vmcnt(0) drains BOTH blocks
      #pragma unroll
      for (int s = 0; s < 16; ++s) {
        short8 b0 = *(const short8*)(lds + T0_OFF + s * 1024 + lane * 16);
        short8 b1 = *(const short8*)(lds + T1_OFF + s * 1024 + lane * 16);
        acc0 = __builtin_amdgcn_mfma_f32_16x16x32_bf16(ax[s], b0, acc0, 0, 0, 0);
        acc1 = __builtin_amdgcn_mfma_f32_16x16x32_bf16(ax[s], b1, acc1, 0, 0, 0);
      }
      #pragma unroll
      for (int s = 16; s < 48; ++s) {
        short8 b0 = *(const short8*)(lds + T0_OFF + s * 1024 + lane * 16);
        short8 b1 = *(const short8*)(lds + T1_OFF + s * 1024 + lane * 16);
        acc0 = __builtin_amdgcn_mfma_f32_16x16x32_bf16(ah[s - 16], b0, acc0, 0, 0, 0);
        acc1 = __builtin_amdgcn_mfma_f32_16x16x32_bf16(ah[s - 16], b1, acc1, 0, 0, 0);
      }
      #pragma unroll
      for (int i = 0; i < 4; ++i) {
        int b = 16 * q + rbase + i;
        float v0 = acc0[i] + bias[nn];        // z or r preact
        float v1 = acc1[i] + bias[16 + nn];   // o preact or Xc(+bias_c)
        if (nn < 8) {
          zbuf[nn * 64 + b] = sigm(v0);
          obuf[nn * 64 + b] = sigm(v1);
        } else {
          int u = nn - 8;
          rcs[u * 64 + b] = sigm(v0) * cst[u * 64 + b];  // r * c_{t-1}
          xcb[u * 64 + b] = v1;                           // Xc + bias_c
        }
      }
    }
    __syncthreads();
    if (tid < 64) {                            // wave 0 packs rc slice -> global
      short8 pk;
      #pragma unroll
      for (int u = 0; u < 8; ++u) pk[u] = (short)f2bf(rcs[u * 64 + tid]);
      cstore16(rcbuf + pc * 65536 + tid * 1024 + 8 * wg, pk);
    }
    if (tid == 0) {                            // all pack stores are wave 0's ops
      vmdrain();
      __hip_atomic_fetch_add(rcctr, 1, __ATOMIC_RELAXED, __HIP_MEMORY_SCOPE_AGENT);
    }

    // ---------- ROUND 2: c_tilde, state update, publish h ----------
    if (tid == 0) {
      const int target = 128 * t;
      while (cload4(rcctr) < target) __builtin_amdgcn_s_sleep(1);
    }
    __syncthreads();

    {
      f32x4 acc = {0.f, 0.f, 0.f, 0.f};
      const unsigned short* rb = rcbuf + pc * 65536 + brow * 1024 + kg8;
      short8 ar[32];
      cload32_w(rb, ar);
      #pragma unroll
      for (int s = 0; s < 32; ++s) {
        short8 bf = *(const short8*)(lds + T2_OFF + s * 1024 + lane * 16);
        acc = __builtin_amdgcn_mfma_f32_16x16x32_bf16(ar[s], bf, acc, 0, 0, 0);
      }
      if (nn < 8) {
        #pragma unroll
        for (int i = 0; i < 4; ++i) {
          int b = 16 * q + rbase + i;
          float ct = tanh_f(acc[i] + xcb[nn * 64 + b]);
          float z  = zbuf[nn * 64 + b];
          float cn = z * cst[nn * 64 + b] + (1.f - z) * ct;
          cst[nn * 64 + b] = cn;
          hst[nn * 64 + b] = obuf[nn * 64 + b] * tanh_f(cn);
        }
      }
    }
    __syncthreads();
    if (t < TSTEPS && tid < 32) {              // convert x for step t+1 (wave 0)
      int e = wg * 256 + tid * 8;
      int b = e >> 9, f = e & 511;
      const float* xs = x + b * 262144 + t * 512 + f;
      short8 pk;
      #pragma unroll
      for (int j = 0; j < 8; ++j) pk[j] = (short)f2bf(xs[j]);
      cstore16(xring + ((t + 1) & 1) * 32768 + b * 512 + f, pk);
    }
    if (tid < 64) {                            // wave 0 packs h -> global
      if (t < TSTEPS) {
        short8 pk;
        #pragma unroll
        for (int u = 0; u < 8; ++u) pk[u] = (short)f2bf(hst[u * 64 + tid]);
        cstore16(hbuf + pc * 65536 + tid * 1024 + 8 * wg, pk);
      } else {                                 // final h as f32, coherent
        f32x4 lo, hi;
        #pragma unroll
        for (int u = 0; u < 4; ++u) { lo[u] = hst[u * 64 + tid]; hi[u] = hst[(u + 4) * 64 + tid]; }
        cstore16f(h32 + tid * 1024 + 8 * wg, lo);
        cstore16f(h32 + tid * 1024 + 8 * wg + 4, hi);
      }
    }
    if (tid == 0) {                            // x + h stores all wave 0 -> one drain
      vmdrain();
      __hip_atomic_fetch_add(hctr, 1, __ATOMIC_RELAXED, __HIP_MEMORY_SCOPE_AGENT);
    }
  }

  // ================= FINAL FC: out = h_T @ fc_w^T + fc_b =================
  if (tid == 0) {
    while (cload4(hctr) < 128 * TSTEPS) __builtin_amdgcn_s_sleep(1);
  }
  __syncthreads();
  __builtin_amdgcn_fence(__ATOMIC_ACQUIRE, "agent");   // one-time inv; h32 via L2 after

  if (wg < 125) {                                // 125 WGs * 8 classes = 1000
    for (int cc = 0; cc < 2; ++cc) {
      int c = 8 * wg + 2 * q + cc;
      const float* wrow = fcw + c * 1024;
      for (int b = 0; b < 64; ++b) {
        const float* hrow = h32 + b * 1024;
        float s = 0.f;
        for (int kk = lane; kk < 1024; kk += 64) s = __builtin_fmaf(hrow[kk], wrow[kk], s);
        #pragma unroll
        for (int off = 32; off; off >>= 1) s += __shfl_xor(s, off);
        if (lane == 0) out[b * 1000 + c] = s + fcb[c];
      }
    }
  }
}

extern "C" void kernel_launch(void* const* d_in, const int* in_sizes, int n_in,
                              void* d_out, int out_size, void* d_ws, size_t ws_size,
                              hipStream_t stream) {
  (void)in_sizes; (void)n_in; (void)out_size; (void)ws_size;
  const float* x   = (const float*)d_in[0];
  const float* Wz  = (const float*)d_in[1];
  const float* bz  = (const float*)d_in[2];
  const float* Wr  = (const float*)d_in[3];
  const float* br  = (const float*)d_in[4];
  const float* Wc  = (const float*)d_in[5];
  const float* bc  = (const float*)d_in[6];
  const float* Wo  = (const float*)d_in[7];
  const float* bo  = (const float*)d_in[8];
  const float* fcw = (const float*)d_in[9];
  const float* fcb = (const float*)d_in[10];

  hipFuncSetAttribute((const void*)lmgru_kernel,
                      hipFuncAttributeMaxDynamicSharedMemorySize, LDS_BYTES);

  hipLaunchKernelGGL(lmgru_kernel, dim3(NWG), dim3(256), LDS_BYTES, stream,
                     x, Wz, bz, Wr, br, Wc, bc, Wo, bo, fcw, fcb,
                     (float*)d_out, (char*)d_ws);
}